// Round 1
// baseline (1415.765 us; speedup 1.0000x reference)
//
#include <hip/hip_runtime.h>
#include <hip/hip_bf16.h>

// Conv4d: B=1, IC=16, OC=32, K=3 (each of 4 dims), stride=1, pad=1, dil=1, D=32.
// out[oc][a][b][c][d] = bias[oc] + sum_{ic,k1..k4} x[ic][a+k1-1][b+k2-1][c+k3-1][d+k4-1] * w[oc][ic][k1][k2][k3][k4]
//
// Strategy (round 1, fp32 baseline): direct conv, LDS-tiled.
// Block = 256 threads: fixed (a,b), c-tile of 4, all d (32), all oc (32).
// Thread tile: 4 oc x 4 d. Per (ic,k1,k2,k3): 6 input floats (float4+float2,
// 16B aligned), 3x float4 weights, 48 FMAs -> VALU-bound by design.

#define IC 16
#define OC 32
#define DD 32
#define KW 3

// LDS layouts (padded inner dims to 36 floats = 144B, multiple of 16B -> aligned
// float4 rows, bank stride 4 -> conflict-free for our access patterns)
#define SX_C 6      // c-halo: c0-1 .. c0+4
#define SX_DPAD 36  // d-halo 34 padded to 36
#define SW_OCPAD 36 // 32 ocs padded to 36

__global__ __launch_bounds__(256, 4) void conv4d_kernel(
    const float* __restrict__ x,     // [IC][32][32][32][32]
    const float* __restrict__ w,     // [OC][IC*81]
    const float* __restrict__ bias,  // [OC]
    float* __restrict__ out)         // [OC][32][32][32][32]
{
    __shared__ __attribute__((aligned(16))) float s_x[3 * 3 * SX_C * SX_DPAD]; // 1944 floats
    __shared__ __attribute__((aligned(16))) float s_w[81 * SW_OCPAD];          // 2916 floats

    // grid: 32 (a) * 32 (b) * 8 (c-blocks) = 8192 blocks
    const int blk  = blockIdx.x;
    const int cblk = blk & 7;
    const int bco  = (blk >> 3) & 31;
    const int aco  = blk >> 8;
    const int c0   = cblk * 4;

    const int tid    = threadIdx.x;
    const int c_idx  = tid >> 6;        // 0..3 (uniform per wave)
    const int r      = tid & 63;
    const int oc_grp = r >> 3;          // 0..7
    const int d_grp  = r & 7;           // 0..7
    const int d0     = d_grp * 4;
    const int oc0    = oc_grp * 4;

    float acc[4][4]; // [oc][d]
#pragma unroll
    for (int j = 0; j < 4; ++j)
#pragma unroll
        for (int i = 0; i < 4; ++i) acc[j][i] = 0.f;

    for (int ic = 0; ic < IC; ++ic) {
        // ---- stage input patch: a-1..a+1, b-1..b+1, c0-1..c0+4, d -1..32 ----
        for (int t = tid; t < 3 * 3 * SX_C * 34; t += 256) {
            int dd = t % 34;
            int r2 = t / 34;
            int cc = r2 % SX_C;
            int r3 = r2 / SX_C;
            int bb = r3 % 3;
            int aa = r3 / 3;
            int ia  = aco + aa - 1;
            int ib  = bco + bb - 1;
            int icc = c0 + cc - 1;
            int idd = dd - 1;
            float v = 0.f;
            if ((unsigned)ia < 32u && (unsigned)ib < 32u &&
                (unsigned)icc < 32u && (unsigned)idd < 32u)
                v = x[(((ic * 32 + ia) * 32 + ib) * 32 + icc) * 32 + idd];
            s_x[((aa * 3 + bb) * SX_C + cc) * SX_DPAD + dd] = v;
        }
        // ---- stage weights for this ic, transposed to [kk][oc] ----
        for (int t = tid; t < 81 * OC; t += 256) {
            int oc = t / 81;
            int kk = t % 81;
            s_w[kk * SW_OCPAD + oc] = w[oc * (IC * 81) + ic * 81 + kk];
        }
        __syncthreads();

        // ---- compute ----
#pragma unroll
        for (int k1 = 0; k1 < 3; ++k1)
#pragma unroll
        for (int k2 = 0; k2 < 3; ++k2)
#pragma unroll
        for (int k3 = 0; k3 < 3; ++k3) {
            const float* xp = &s_x[((k1 * 3 + k2) * SX_C + (c_idx + k3)) * SX_DPAD + d0];
            const float4 xa = *(const float4*)xp;        // d0..d0+3
            const float2 xb = *(const float2*)(xp + 4);  // d0+4..d0+5
            float xv[6] = {xa.x, xa.y, xa.z, xa.w, xb.x, xb.y};
            const float* wp = &s_w[(((k1 * 3 + k2) * 3 + k3) * 3) * SW_OCPAD + oc0];
#pragma unroll
            for (int k4 = 0; k4 < 3; ++k4) {
                const float4 wv = *(const float4*)(wp + k4 * SW_OCPAD);
#pragma unroll
                for (int dd = 0; dd < 4; ++dd) {
                    float xval = xv[dd + k4];
                    acc[0][dd] += xval * wv.x;
                    acc[1][dd] += xval * wv.y;
                    acc[2][dd] += xval * wv.z;
                    acc[3][dd] += xval * wv.w;
                }
            }
        }
        __syncthreads();
    }

    // ---- epilogue: bias + vectorized store ----
    const int cc_out = c0 + c_idx;
#pragma unroll
    for (int j = 0; j < 4; ++j) {
        int oc = oc0 + j;
        float bv = bias[oc];
        float4 v = make_float4(acc[j][0] + bv, acc[j][1] + bv,
                               acc[j][2] + bv, acc[j][3] + bv);
        float* op = &out[(((oc * 32 + aco) * 32 + bco) * 32 + cc_out) * 32 + d0];
        *(float4*)op = v;
    }
}

extern "C" void kernel_launch(void* const* d_in, const int* in_sizes, int n_in,
                              void* d_out, int out_size, void* d_ws, size_t ws_size,
                              hipStream_t stream) {
    const float* x    = (const float*)d_in[0];  // [1,16,32,32,32,32]
    const float* w    = (const float*)d_in[1];  // [32, 16*81]
    const float* bias = (const float*)d_in[2];  // [1,32,1,1,1,1]
    float* out        = (float*)d_out;          // [1,32,32,32,32,32]

    conv4d_kernel<<<dim3(32 * 32 * 8), dim3(256), 0, stream>>>(x, w, bias, out);
}

// Round 2
// 408.799 us; speedup vs baseline: 3.4632x; 3.4632x over previous
//
#include <hip/hip_runtime.h>
#include <hip/hip_bf16.h>
#include <stdint.h>

// Conv4d B=1 IC=16 OC=32 K=3^4 pad=1 stride=1, D=32 -> implicit GEMM on MFMA.
// D[m=oc(32)][n=d(32)] per mfma_f32_32x32x16_bf16; K=16 = 2 delta-slots x 8 ic.
// Block tile: (2a,2b,4c,32d); 4 waves, wave=(ai,bi), 4 c-subtiles each.
// LDS: s_x [96 rows][34 d'][8 ic] bf16 (52224 B, 16B/point -> conflict-free b128),
//      s_w 2 x [10 slots][32 oc][8 ic] bf16 (10240 B, double-buffered per (da,db)).
// ic staged in 2 groups of 8 (keeps LDS at 62.4 KB -> 2 blocks/CU, 2 waves/SIMD).

typedef __bf16 bf16x8 __attribute__((ext_vector_type(8)));
typedef float f32x16 __attribute__((ext_vector_type(16)));

#define X_IC_STRIDE 1048576  // 32^4 elements per ic plane
#define W_K 1296             // 16 * 81
#define SX_BYTES 52224       // 96*34*16
#define SW_OFF SX_BYTES
#define SW_BUF 5120          // 10*32*16

__global__ __launch_bounds__(256, 2) void conv4d_mfma(
    const float* __restrict__ x,     // [16][32][32][32][32]
    const float* __restrict__ w,     // [32][1296]
    const float* __restrict__ bias,  // [32]
    float* __restrict__ out)         // [32][32][32][32][32]
{
    __shared__ __attribute__((aligned(16))) unsigned char lds[SX_BYTES + 2 * SW_BUF];

    const int tid  = threadIdx.x;
    const int lane = tid & 63;
    const int wv   = tid >> 6;     // wave 0..3
    const int kh   = lane >> 5;    // k-half (selects slot of the pair)
    const int ln   = lane & 31;    // A: oc ; B: d

    // grid: 16(a) * 16(b) * 8(c) = 2048 blocks
    const int blk = blockIdx.x;
    const int c0  = (blk & 7) * 4;
    const int b0  = ((blk >> 3) & 15) * 2;
    const int a0  = (blk >> 7) * 2;
    const int ai  = wv >> 1, bi = wv & 1;

    // per-lane: for pair p, slot = 2p+kh -> (dc,dd); dummy slot 9 -> (2,2), B*0
    int pbase[5];
#pragma unroll
    for (int p = 0; p < 5; ++p) {
        int slot = 2 * p + kh;
        int dc = (slot >= 9) ? 2 : slot / 3;
        int dd = (slot >= 9) ? 2 : slot - (slot / 3) * 3;
        pbase[p] = dc * (34 * 16) + (ln + dd) * 16;
    }
    const int wrd_base = SW_OFF + kh * 512 + ln * 16;  // + wb*5120 + p*1024

    // bias per C/D reg: oc(r) = (r&3) + 8*(r>>2) + 4*kh
    float bv[16];
#pragma unroll
    for (int r = 0; r < 16; ++r) bv[r] = bias[(r & 3) + 8 * (r >> 2) + 4 * kh];

    f32x16 acc[4];
#pragma unroll
    for (int ci = 0; ci < 4; ++ci)
#pragma unroll
        for (int r = 0; r < 16; ++r) acc[ci][r] = 0.f;

    auto stage_x = [&](int g) {
        for (int t = tid; t < 96 * 34; t += 256) {
            int dpr = t % 34;
            int row = t / 34;
            int rc = row % 6; int r2 = row / 6;
            int rb = r2 & 3;  int ra = r2 >> 2;
            int a_in = a0 + ra - 1, b_in = b0 + rb - 1;
            int c_in = c0 + rc - 1, d_in = dpr - 1;
            uint4 pk = make_uint4(0u, 0u, 0u, 0u);
            if ((unsigned)a_in < 32u && (unsigned)b_in < 32u &&
                (unsigned)c_in < 32u && (unsigned)d_in < 32u) {
                const float* xp = x + (size_t)(g * 8) * X_IC_STRIDE +
                                  (((a_in * 32 + b_in) * 32 + c_in) * 32 + d_in);
                unsigned u[8];
#pragma unroll
                for (int j = 0; j < 8; ++j) {
                    unsigned b = __builtin_bit_cast(unsigned, xp[j * X_IC_STRIDE]);
                    u[j] = (b + 0x7FFFu + ((b >> 16) & 1u)) >> 16;  // RNE to bf16
                }
                pk.x = u[0] | (u[1] << 16); pk.y = u[2] | (u[3] << 16);
                pk.z = u[4] | (u[5] << 16); pk.w = u[6] | (u[7] << 16);
            }
            *(uint4*)(lds + t * 16) = pk;
        }
    };

    auto stage_w = [&](int g, int dadb, int wb) {
        int da = dadb / 3, db = dadb - (dadb / 3) * 3;
        for (int t = tid; t < 1280; t += 256) {       // 10*32*4 ic-pairs
            int icp  = t & 3;
            int oc_  = (t >> 2) & 31;
            int slot = t >> 7;                         // 0..9
            unsigned pk = 0u;
            if (slot < 9) {
                int dc = slot / 3, dd = slot - (slot / 3) * 3;
                int koff = da * 27 + db * 9 + dc * 3 + dd;
                const float* wp = w + oc_ * W_K + (g * 8 + icp * 2) * 81 + koff;
                unsigned bl = __builtin_bit_cast(unsigned, wp[0]);
                unsigned bh = __builtin_bit_cast(unsigned, wp[81]);
                bl = (bl + 0x7FFFu + ((bl >> 16) & 1u)) >> 16;
                bh = (bh + 0x7FFFu + ((bh >> 16) & 1u)) >> 16;
                pk = bl | (bh << 16);
            }
            *(unsigned*)(lds + SW_OFF + wb * SW_BUF + slot * 512 + oc_ * 16 + icp * 4) = pk;
        }
    };

    for (int g = 0; g < 2; ++g) {
        stage_x(g);
        stage_w(g, 0, 0);
        __syncthreads();
        for (int dadb = 0; dadb < 9; ++dadb) {
            if (dadb < 8) stage_w(g, dadb + 1, (dadb + 1) & 1);  // overlap w/ compute
            int da = dadb / 3, db = dadb - (dadb / 3) * 3;
            int ubase = ((ai + da) * 24 + (bi + db) * 6) * 544;  // row*544
            int wb = dadb & 1;
#pragma unroll
            for (int p = 0; p < 5; ++p) {
                bf16x8 afrag = *(const bf16x8*)(lds + wrd_base + wb * SW_BUF + p * 1024);
                int baddr = ubase + pbase[p];
#pragma unroll
                for (int ci = 0; ci < 4; ++ci) {
                    bf16x8 bfrag = *(const bf16x8*)(lds + baddr + ci * 544);
                    acc[ci] = __builtin_amdgcn_mfma_f32_32x32x16_bf16(
                        afrag, bfrag, acc[ci], 0, 0, 0);
                }
            }
            __syncthreads();
        }
    }

    // epilogue: D col = lane&31 = d (coalesced), row = oc = (r&3)+8*(r>>2)+4*kh
    const size_t sp_base = (((size_t)(a0 + ai) * 32 + (b0 + bi)) * 32 + c0);
#pragma unroll
    for (int ci = 0; ci < 4; ++ci) {
#pragma unroll
        for (int r = 0; r < 16; ++r) {
            int oc_ = (r & 3) + 8 * (r >> 2) + 4 * kh;
            out[(size_t)oc_ * X_IC_STRIDE + (sp_base + ci) * 32 + ln] = acc[ci][r] + bv[r];
        }
    }
}

extern "C" void kernel_launch(void* const* d_in, const int* in_sizes, int n_in,
                              void* d_out, int out_size, void* d_ws, size_t ws_size,
                              hipStream_t stream) {
    const float* x    = (const float*)d_in[0];
    const float* w    = (const float*)d_in[1];
    const float* bias = (const float*)d_in[2];
    float* out        = (float*)d_out;

    conv4d_mfma<<<dim3(2048), dim3(256), 0, stream>>>(x, w, bias, out);
}

// Round 3
// 276.150 us; speedup vs baseline: 5.1268x; 1.4804x over previous
//
#include <hip/hip_runtime.h>
#include <hip/hip_bf16.h>
#include <stdint.h>

// Conv4d B=1 IC=16 OC=32 K=3^4 pad=1 stride=1, D=32 -> implicit GEMM on MFMA.
// Round 3: weights pre-packed to d_ws as bf16 A-fragments (one dwordx4 per
// wave-lane per frag, L2-hot, register double-buffered). LDS holds x only
// (52224 B -> 3 blocks/CU). 4 barriers per block (2 per ic-group).
// Compute structure + verified C/D layout identical to round 2.

typedef __bf16 bf16x8 __attribute__((ext_vector_type(8)));
typedef float f32x16 __attribute__((ext_vector_type(16)));

#define X_IC_STRIDE 1048576  // 32^4 elements per ic plane
#define W_K 1296             // 16 * 81
#define SX_BYTES 52224       // 96 rows * 34 pts * 16 B
#define WPACK_DWORDS 23040   // 90 frags * 256 dwords (92160 B)

__device__ __forceinline__ unsigned rne_bf16(float f) {
    unsigned b = __builtin_bit_cast(unsigned, f);
    return (b + 0x7FFFu + ((b >> 16) & 1u)) >> 16;
}

// Pack w[32][1296] fp32 -> wpack: 90 frags of 1024 B.
// frag fi = (g*9 + dadb)*5 + p ; within frag: lane(kh*32+oc)*16B + icpair*4B.
// slot = 2p+kh ; slot 9 = zero pad.
__global__ void pack_w_kernel(const float* __restrict__ w, unsigned* __restrict__ wpack) {
    int D = blockIdx.x * 256 + threadIdx.x;
    if (D >= WPACK_DWORDS) return;
    int t    = D & 3;          // ic pair
    int lane = (D >> 2) & 63;
    int fi   = D >> 8;
    int p    = fi % 5;
    int dadb = (fi / 5) % 9;
    int g    = fi / 45;
    int kh   = lane >> 5;
    int oc   = lane & 31;
    int slot = 2 * p + kh;
    unsigned pk = 0u;
    if (slot < 9) {
        int da = dadb / 3, db = dadb % 3;
        int dc = slot / 3, dd = slot % 3;
        int koff = da * 27 + db * 9 + dc * 3 + dd;
        int ic0  = g * 8 + 2 * t;
        unsigned lo = rne_bf16(w[oc * W_K + ic0 * 81 + koff]);
        unsigned hi = rne_bf16(w[oc * W_K + (ic0 + 1) * 81 + koff]);
        pk = lo | (hi << 16);
    }
    wpack[D] = pk;
}

__global__ __launch_bounds__(256, 3) void conv4d_mfma(
    const float* __restrict__ x,         // [16][32][32][32][32]
    const unsigned char* __restrict__ wpack,
    const float* __restrict__ bias,      // [32]
    float* __restrict__ out)             // [32][32][32][32][32]
{
    __shared__ __attribute__((aligned(16))) unsigned char lds[SX_BYTES];

    const int tid  = threadIdx.x;
    const int lane = tid & 63;
    const int wv   = tid >> 6;     // wave 0..3
    const int kh   = lane >> 5;    // k-half -> slot select
    const int ln   = lane & 31;    // A: oc ; B: d

    // grid: 16(a) * 16(b) * 8(c) = 2048 blocks
    const int blk = blockIdx.x;
    const int c0  = (blk & 7) * 4;
    const int b0  = ((blk >> 3) & 15) * 2;
    const int a0  = (blk >> 7) * 2;
    const int ai  = wv >> 1, bi = wv & 1;

    // per-lane b-frag bases: slot = 2p+kh -> (dc,dd); dummy slot 9 -> (2,2) (x *0-weight)
    int pbase[5];
#pragma unroll
    for (int p = 0; p < 5; ++p) {
        int slot = 2 * p + kh;
        int dc = (slot >= 9) ? 2 : slot / 3;
        int dd = (slot >= 9) ? 2 : slot % 3;
        pbase[p] = dc * 544 + (ln + dd) * 16;
    }

    float bv[16];
#pragma unroll
    for (int r = 0; r < 16; ++r) bv[r] = bias[(r & 3) + 8 * (r >> 2) + 4 * kh];

    f32x16 acc[4];
#pragma unroll
    for (int ci = 0; ci < 4; ++ci)
#pragma unroll
        for (int r = 0; r < 16; ++r) acc[ci][r] = 0.f;

    // ---- prime a-frag register buffer for fi=0 ----
    bf16x8 af[5];
#pragma unroll
    for (int p = 0; p < 5; ++p)
        af[p] = *(const bf16x8*)(wpack + (size_t)p * 1024 + lane * 16);

    for (int g = 0; g < 2; ++g) {
        if (g) __syncthreads();  // protect LDS before restage
        // ---- stage x tile: rows (4a x 4b x 6c), 34 d-pts, 8 ic bf16 per pt ----
        for (int t = tid; t < 96 * 34; t += 256) {
            int dpr = t % 34;
            int row = t / 34;
            int rc = row % 6; int r2 = row / 6;
            int rb = r2 & 3;  int ra = r2 >> 2;
            int a_in = a0 + ra - 1, b_in = b0 + rb - 1;
            int c_in = c0 + rc - 1, d_in = dpr - 1;
            uint4 pk = make_uint4(0u, 0u, 0u, 0u);
            if ((unsigned)a_in < 32u && (unsigned)b_in < 32u &&
                (unsigned)c_in < 32u && (unsigned)d_in < 32u) {
                const float* xp = x + (size_t)(g * 8) * X_IC_STRIDE +
                                  (((a_in * 32 + b_in) * 32 + c_in) * 32 + d_in);
                unsigned u[8];
#pragma unroll
                for (int j = 0; j < 8; ++j)
                    u[j] = rne_bf16(xp[j * X_IC_STRIDE]);
                pk.x = u[0] | (u[1] << 16); pk.y = u[2] | (u[3] << 16);
                pk.z = u[4] | (u[5] << 16); pk.w = u[6] | (u[7] << 16);
            }
            *(uint4*)(lds + t * 16) = pk;
        }
        __syncthreads();

        for (int dadb = 0; dadb < 9; ++dadb) {
            const int fi  = g * 9 + dadb;
            const int nfi = (fi + 1 > 17) ? 17 : fi + 1;
            // prefetch next phase's a-frags (register double buffer)
            bf16x8 afn[5];
#pragma unroll
            for (int p = 0; p < 5; ++p)
                afn[p] = *(const bf16x8*)(wpack + ((size_t)nfi * 5 + p) * 1024 + lane * 16);

            const int da = dadb / 3, db = dadb % 3;
            const int ubase = ((ai + da) * 24 + (bi + db) * 6) * 544;
#pragma unroll
            for (int p = 0; p < 5; ++p) {
                const unsigned char* bp = lds + ubase + pbase[p];
#pragma unroll
                for (int ci = 0; ci < 4; ++ci) {
                    bf16x8 bfrag = *(const bf16x8*)(bp + ci * 544);
                    acc[ci] = __builtin_amdgcn_mfma_f32_32x32x16_bf16(
                        af[p], bfrag, acc[ci], 0, 0, 0);
                }
            }
#pragma unroll
            for (int p = 0; p < 5; ++p) af[p] = afn[p];
        }
    }

    // epilogue: D col = lane&31 = d (coalesced), row = oc = (r&3)+8*(r>>2)+4*kh
    const size_t sp_base = (((size_t)(a0 + ai) * 32 + (b0 + bi)) * 32 + c0);
#pragma unroll
    for (int ci = 0; ci < 4; ++ci) {
#pragma unroll
        for (int r = 0; r < 16; ++r) {
            int oc_ = (r & 3) + 8 * (r >> 2) + 4 * kh;
            out[(size_t)oc_ * X_IC_STRIDE + (sp_base + ci) * 32 + ln] = acc[ci][r] + bv[r];
        }
    }
}

extern "C" void kernel_launch(void* const* d_in, const int* in_sizes, int n_in,
                              void* d_out, int out_size, void* d_ws, size_t ws_size,
                              hipStream_t stream) {
    const float* x    = (const float*)d_in[0];
    const float* w    = (const float*)d_in[1];
    const float* bias = (const float*)d_in[2];
    float* out        = (float*)d_out;
    unsigned* wpack   = (unsigned*)d_ws;   // 92160 B used

    pack_w_kernel<<<dim3((WPACK_DWORDS + 255) / 256), dim3(256), 0, stream>>>(w, wpack);
    conv4d_mfma<<<dim3(2048), dim3(256), 0, stream>>>(
        x, (const unsigned char*)d_ws, bias, out);
}